// Round 4
// baseline (634.208 us; speedup 1.0000x reference)
//
#include <hip/hip_runtime.h>
#include <hip/hip_bf16.h>

#define BATCH 2
#define SEQ   2048
#define DMODEL 1024
#define NHEAD 16
#define DEPTH 64
#define NBANDS 7

// Allowed diffs: causal AND (local<=32 OR |log2(d)-round|<0.1), derived exactly:
//   [0,34] [60,68] [120,137] [239,274] [478,548] [956,1097] [1911,2047]
__device__ __constant__ int cBLO[NBANDS] = {0, 60, 120, 239, 478, 956, 1911};
__device__ __constant__ int cBHI[NBANDS] = {34, 68, 137, 274, 548, 1097, 2047};

typedef __attribute__((ext_vector_type(4))) float f32x4;
typedef __attribute__((ext_vector_type(8))) short bf16x8;
#define MFMA16(a, b, c) __builtin_amdgcn_mfma_f32_16x16x32_bf16(a, b, c, 0, 0, 0)

__device__ __forceinline__ unsigned short f2bf(float x) {
    unsigned int u = __float_as_uint(x);
    u += 0x7fffu + ((u >> 16) & 1u);   // RNE
    return (unsigned short)(u >> 16);
}
__device__ __forceinline__ float bf2f(unsigned short h) {
    return __uint_as_float((unsigned int)h << 16);
}

// ---------------------------------------------------------------------------
// split convert: x f32 [4096][1024] -> out bf16 [4096][3072] = [hi | lo | hi]
// ---------------------------------------------------------------------------
__global__ __launch_bounds__(256) void cvt_split(
    const float* __restrict__ x, unsigned short* __restrict__ out)
{
    size_t t = (size_t)blockIdx.x * 256 + threadIdx.x;   // < 524288
    size_t f = t * 8;
    int m = (int)(f >> 10), kk = (int)(f & 1023);
    float4 v0 = *(const float4*)(x + f);
    float4 v1 = *(const float4*)(x + f + 4);
    float v[8] = {v0.x, v0.y, v0.z, v0.w, v1.x, v1.y, v1.z, v1.w};
    unsigned short hi[8], lo[8];
    #pragma unroll
    for (int j = 0; j < 8; ++j) {
        hi[j] = f2bf(v[j]);
        lo[j] = f2bf(v[j] - bf2f(hi[j]));
    }
    unsigned short* row = out + (size_t)m * 3072 + kk;
    *(uint4*)row          = *(uint4*)hi;
    *(uint4*)(row + 2048) = *(uint4*)hi;
    *(uint4*)(row + 1024) = *(uint4*)lo;
}

// plain convert: f32 [4096][1024] -> bf16 [4096][1024]
__global__ __launch_bounds__(256) void cvt_plain(
    const float* __restrict__ x, unsigned short* __restrict__ out)
{
    size_t t = (size_t)blockIdx.x * 256 + threadIdx.x;
    size_t f = t * 8;
    float4 v0 = *(const float4*)(x + f);
    float4 v1 = *(const float4*)(x + f + 4);
    float v[8] = {v0.x, v0.y, v0.z, v0.w, v1.x, v1.y, v1.z, v1.w};
    unsigned short hi[8];
    #pragma unroll
    for (int j = 0; j < 8; ++j) hi[j] = f2bf(v[j]);
    *(uint4*)(out + f) = *(uint4*)hi;
}

// ---------------------------------------------------------------------------
// weight transpose+convert: W f32 [1024][1024] -> WT bf16 [1024][Kout]
// SPLIT: WT[n] = [Whi(k) | Whi(k) | Wlo(k)] (Kout=3072); else hi only (1024).
// ---------------------------------------------------------------------------
template<int SPLIT>
__global__ __launch_bounds__(256) void cvt_wT(
    const float* __restrict__ W, unsigned short* __restrict__ WT)
{
    const int k0 = blockIdx.x * 64, n0 = blockIdx.y * 64;
    __shared__ float T[64][65];
    const int t = threadIdx.x;
    const int r = t >> 2, cc = (t & 3) * 16;
    {
        const float* src = W + (size_t)(k0 + r) * 1024 + n0 + cc;
        #pragma unroll
        for (int j = 0; j < 4; ++j) {
            float4 a = *(const float4*)(src + 4 * j);
            T[r][cc + 4 * j + 0] = a.x; T[r][cc + 4 * j + 1] = a.y;
            T[r][cc + 4 * j + 2] = a.z; T[r][cc + 4 * j + 3] = a.w;
        }
    }
    __syncthreads();
    const int d = t >> 2;                     // local n
    unsigned short hi[16], lo[16];
    #pragma unroll
    for (int j = 0; j < 16; ++j) {
        float v = T[cc + j][d];
        hi[j] = f2bf(v);
        if (SPLIT) lo[j] = f2bf(v - bf2f(hi[j]));
    }
    const int Kout = SPLIT ? 3072 : 1024;
    unsigned short* dst = WT + (size_t)(n0 + d) * Kout + k0 + cc;
    *(uint4*)dst       = *(uint4*)hi;
    *(uint4*)(dst + 8) = *(uint4*)(hi + 8);
    if (SPLIT) {
        *(uint4*)(dst + 1024)     = *(uint4*)hi;
        *(uint4*)(dst + 1024 + 8) = *(uint4*)(hi + 8);
        *(uint4*)(dst + 2048)     = *(uint4*)lo;
        *(uint4*)(dst + 2048 + 8) = *(uint4*)(lo + 8);
    }
}

// ---------------------------------------------------------------------------
// bf16 MFMA GEMM: C[M,1024] = A[M,Kc] @ BT[1024,Kc]^T + bias, optional scale.
// 128x128 tile, BK=64, 256 threads = 4 waves (2x2), reg-staged XOR-swz LDS.
// ---------------------------------------------------------------------------
template<int OUT_BF16>
__global__ __launch_bounds__(256) void gemm_mfma(
    const unsigned short* __restrict__ A, const unsigned short* __restrict__ BT,
    const float* __restrict__ bias, void* __restrict__ Cout,
    int Kc, float scale)
{
    __shared__ unsigned short Atile[128 * 64];
    __shared__ unsigned short Btile[128 * 64];
    const int tid  = threadIdx.x;
    const int lane = tid & 63;
    const int wave = tid >> 6;
    const int wm = (wave >> 1) * 64;
    const int wn = (wave & 1) * 64;
    const int rowBase = blockIdx.y * 128;
    const int colBase = blockIdx.x * 128;

    f32x4 acc[4][4];
    #pragma unroll
    for (int mt = 0; mt < 4; ++mt)
        #pragma unroll
        for (int nt = 0; nt < 4; ++nt) {
            acc[mt][nt].x = 0.f; acc[mt][nt].y = 0.f;
            acc[mt][nt].z = 0.f; acc[mt][nt].w = 0.f;
        }

    const int srow = tid >> 3;            // 0..31 (+32 per i)
    const int sch  = tid & 7;
    uint4 ar[4], br[4];

    #define ISSUE(k0)                                                          \
        _Pragma("unroll")                                                      \
        for (int i = 0; i < 4; ++i) {                                          \
            int row = srow + i * 32;                                           \
            ar[i] = *(const uint4*)(A  + (size_t)(rowBase + row) * Kc + (k0) + sch * 8); \
            br[i] = *(const uint4*)(BT + (size_t)(colBase + row) * Kc + (k0) + sch * 8); \
        }

    ISSUE(0)
    const int nk = Kc >> 6;
    for (int t = 0; t < nk; ++t) {
        __syncthreads();
        #pragma unroll
        for (int i = 0; i < 4; ++i) {
            int row = srow + i * 32;
            int off = row * 128 + ((sch * 16) ^ ((row & 7) << 4));
            *(uint4*)((char*)Atile + off) = ar[i];
            *(uint4*)((char*)Btile + off) = br[i];
        }
        __syncthreads();
        if (t + 1 < nk) { int k0n = (t + 1) << 6; ISSUE(k0n) }

        bf16x8 a0[4], a1[4];
        const int g = (lane >> 4) * 16;
        #pragma unroll
        for (int mt = 0; mt < 4; ++mt) {
            int arow = wm + mt * 16 + (lane & 15);
            const char* base = (const char*)Atile + arow * 128;
            int sw = (arow & 7) << 4;
            a0[mt] = *(const bf16x8*)(base + (g ^ sw));
            a1[mt] = *(const bf16x8*)(base + ((g + 64) ^ sw));
        }
        #pragma unroll
        for (int nt = 0; nt < 4; ++nt) {
            int brow = wn + nt * 16 + (lane & 15);
            const char* base = (const char*)Btile + brow * 128;
            int sw = (brow & 7) << 4;
            bf16x8 b0 = *(const bf16x8*)(base + (g ^ sw));
            bf16x8 b1 = *(const bf16x8*)(base + ((g + 64) ^ sw));
            #pragma unroll
            for (int mt = 0; mt < 4; ++mt) {
                acc[mt][nt] = MFMA16(a0[mt], b0, acc[mt][nt]);
                acc[mt][nt] = MFMA16(a1[mt], b1, acc[mt][nt]);
            }
        }
    }
    #undef ISSUE

    #pragma unroll
    for (int nt = 0; nt < 4; ++nt) {
        int col = colBase + wn + nt * 16 + (lane & 15);
        float bv = bias[col];
        #pragma unroll
        for (int mt = 0; mt < 4; ++mt) {
            #pragma unroll
            for (int r = 0; r < 4; ++r) {
                int row = rowBase + wm + mt * 16 + (lane >> 4) * 4 + r;
                float val = (acc[mt][nt][r] + bv) * scale;
                if (OUT_BF16)
                    ((unsigned short*)Cout)[(size_t)row * 1024 + col] = f2bf(val);
                else
                    ((float*)Cout)[(size_t)row * 1024 + col] = val;
            }
        }
    }
}

// ---------------------------------------------------------------------------
// V transpose+convert: vh f32 [b][c][h*64+d] -> vbT bf16 [b][h][d][c]
// ---------------------------------------------------------------------------
__global__ __launch_bounds__(256) void convert_vT(
    const float* __restrict__ vh, unsigned short* __restrict__ vbT)
{
    const int ct = blockIdx.x, h = blockIdx.y, b = blockIdx.z;
    const int c0 = ct * 64;
    __shared__ float T[64][65];
    const int tid = threadIdx.x;
    {
        int r = tid >> 2, dc = (tid & 3) * 16;
        const float* src = vh + ((size_t)(b * SEQ + c0 + r)) * DMODEL + h * DEPTH + dc;
        #pragma unroll
        for (int j = 0; j < 4; ++j) {
            float4 a = *(const float4*)(src + 4 * j);
            T[r][dc + 4 * j + 0] = a.x;
            T[r][dc + 4 * j + 1] = a.y;
            T[r][dc + 4 * j + 2] = a.z;
            T[r][dc + 4 * j + 3] = a.w;
        }
    }
    __syncthreads();
    {
        int d = tid >> 2, cc = (tid & 3) * 16;
        unsigned int w[8];
        #pragma unroll
        for (int j = 0; j < 8; ++j) {
            unsigned short lo = f2bf(T[cc + 2 * j][d]);
            unsigned short hi = f2bf(T[cc + 2 * j + 1][d]);
            w[j] = (unsigned int)lo | ((unsigned int)hi << 16);
        }
        unsigned short* dst = vbT + ((size_t)((b * NHEAD + h) * DEPTH + d)) * SEQ + c0 + cc;
        uint4 o0 = {w[0], w[1], w[2], w[3]};
        uint4 o1 = {w[4], w[5], w[6], w[7]};
        *(uint4*)dst = o0;
        *(uint4*)(dst + 8) = o1;
    }
}

// ---------------------------------------------------------------------------
// stage a 64x64 bf16 tile into LDS (128B rows) with G4 XOR swizzle
// ---------------------------------------------------------------------------
__device__ __forceinline__ void stage64x64(
    unsigned short* dst, const unsigned short* __restrict__ src,
    int srcStride, int tid)
{
    #pragma unroll
    for (int t = tid; t < 512; t += 256) {
        int row = t >> 3, ch = t & 7;
        uint4 v = *(const uint4*)(src + (size_t)row * srcStride + ch * 8);
        *(uint4*)((char*)dst + row * 128 + ((ch * 16) ^ ((row & 7) << 4))) = v;
    }
}

// ---------------------------------------------------------------------------
// MFMA attention, swapped-operand QK^T (S^T = K·Q^T): each lane owns one
// q-row and 4 consecutive k-cols per fragment -> float4 attn stores,
// b64 P writes, register row-mask (funnel shift of reversed bitmask).
// Pass 1: row sums. Pass 2: recompute, write normalized attn + PV.
// ---------------------------------------------------------------------------
__global__ __launch_bounds__(256) void attn_mfma(
    const unsigned short* __restrict__ qb, const unsigned short* __restrict__ kb,
    const unsigned short* __restrict__ vbT,
    float* __restrict__ attn, unsigned short* __restrict__ ctxb)
{
    const int tid  = threadIdx.x;
    const int lane = tid & 63;
    const int wave = tid >> 6;
    const int g    = lane >> 4;          // 0..3
    const int qt = blockIdx.x, h = blockIdx.y, b = blockIdx.z;
    const int i0 = qt * 64;

    __shared__ unsigned short K_lds[64 * 64];
    __shared__ unsigned short V_lds[64 * 64];
    __shared__ unsigned short P_lds[4][16 * 64];
    __shared__ unsigned long long RBp[34];   // reversed allowed-mask, zero-padded

    // RBp bit (64w+j) = allowed(2047 - 64w - j); words 32,33 = 0
    if (tid < 34) {
        unsigned long long w = 0;
        if (tid < 32) {
            for (int j = 0; j < 64; ++j) {
                int d = 2047 - tid * 64 - j;
                bool a = false;
                #pragma unroll
                for (int bb = 0; bb < NBANDS; ++bb)
                    a = a || (d >= cBLO[bb] && d <= cBHI[bb]);
                if (a) w |= (1ull << j);
            }
        }
        RBp[tid] = w;
    }

    // active-chunk mask (uniform): only c0 <= i0 can be active (causal, 64-aligned)
    unsigned int amask = 0;
    for (int ch = 0; ch < 32; ++ch) {
        int c0 = ch * 64;
        bool act = false;
        #pragma unroll
        for (int bb = 0; bb < NBANDS; ++bb)
            act = act || ((c0 <= i0 + 63 - cBLO[bb]) && (c0 + 63 >= i0 - cBHI[bb]));
        if (act) amask |= (1u << ch);
    }

    // this lane's q-row; Q fragments (B-operand): k-offset 8g along D
    const int i_row = i0 + wave * 16 + (lane & 15);
    const unsigned short* qptr =
        qb + ((size_t)(b * SEQ + i_row)) * DMODEL + h * DEPTH + g * 8;
    bf16x8 qf0 = *(const bf16x8*)qptr;          // d = 8g .. 8g+7
    bf16x8 qf1 = *(const bf16x8*)(qptr + 32);   // d = 32+8g ..

    // ---------------- pass 1: row sum ----------------
    float rs = 0.f;
    for (int ch = 0; ch < 32; ++ch) {
        if (!((amask >> ch) & 1u)) continue;
        const int c0 = ch * 64;
        __syncthreads();
        stage64x64(K_lds, kb + ((size_t)(b * SEQ + c0)) * DMODEL + h * DEPTH, DMODEL, tid);
        __syncthreads();

        // row-mask: bit j = allowed at col c0+j for row i_row
        const int basebit = 2047 - (i_row - c0);
        const int wo = basebit >> 6, sh = basebit & 63;
        unsigned long long rm = sh
            ? ((RBp[wo] >> sh) | (RBp[wo + 1] << (64 - sh)))
            : RBp[wo];

        #pragma unroll
        for (int nt = 0; nt < 4; ++nt) {
            int krow = nt * 16 + (lane & 15);
            const char* kbase = (const char*)K_lds + krow * 128;
            int sw = (krow & 7) << 4;
            bf16x8 ka0 = *(const bf16x8*)(kbase + ((g * 16) ^ sw));
            bf16x8 ka1 = *(const bf16x8*)(kbase + ((g * 16 + 64) ^ sw));
            f32x4 s = {0.f, 0.f, 0.f, 0.f};
            s = MFMA16(ka0, qf0, s);
            s = MFMA16(ka1, qf1, s);
            unsigned nib = (unsigned)(rm >> (nt * 16 + g * 4)) & 0xFu;
            #pragma unroll
            for (int r = 0; r < 4; ++r)
                rs += ((nib >> r) & 1u) ? __expf(s[r]) : 0.f;
        }
    }
    rs += __shfl_xor(rs, 16);
    rs += __shfl_xor(rs, 32);
    const float rsinv = 1.0f / rs;   // d=0 always allowed -> rs > 0

    // ---------------- pass 2: attn write + PV ----------------
    f32x4 o[4];
    #pragma unroll
    for (int dt = 0; dt < 4; ++dt) { o[dt].x = 0.f; o[dt].y = 0.f; o[dt].z = 0.f; o[dt].w = 0.f; }

    float* ablock = attn + ((size_t)((b * NHEAD + h) * SEQ)) * SEQ;
    float* arow = ablock + (size_t)i_row * SEQ;

    for (int ch = 0; ch < 32; ++ch) {
        const int c0 = ch * 64;
        if (!((amask >> ch) & 1u)) {
            float4 z = {0.f, 0.f, 0.f, 0.f};
            #pragma unroll
            for (int t = 0; t < 4; ++t)
                *(float4*)(arow + c0 + g * 16 + t * 4) = z;
            continue;
        }
        __syncthreads();
        stage64x64(K_lds, kb + ((size_t)(b * SEQ + c0)) * DMODEL + h * DEPTH, DMODEL, tid);
        stage64x64(V_lds, vbT + ((size_t)((b * NHEAD + h) * DEPTH)) * SEQ + c0, SEQ, tid);
        __syncthreads();

        const int basebit = 2047 - (i_row - c0);
        const int wo = basebit >> 6, sh = basebit & 63;
        unsigned long long rm = sh
            ? ((RBp[wo] >> sh) | (RBp[wo + 1] << (64 - sh)))
            : RBp[wo];

        char* prow = (char*)&P_lds[wave][0] + (lane & 15) * 128;
        const int swp = ((lane & 15) & 7) << 4;

        #pragma unroll
        for (int nt = 0; nt < 4; ++nt) {
            int krow = nt * 16 + (lane & 15);
            const char* kbase = (const char*)K_lds + krow * 128;
            int sw = (krow & 7) << 4;
            bf16x8 ka0 = *(const bf16x8*)(kbase + ((g * 16) ^ sw));
            bf16x8 ka1 = *(const bf16x8*)(kbase + ((g * 16 + 64) ^ sw));
            f32x4 s = {0.f, 0.f, 0.f, 0.f};
            s = MFMA16(ka0, qf0, s);
            s = MFMA16(ka1, qf1, s);
            unsigned nib = (unsigned)(rm >> (nt * 16 + g * 4)) & 0xFu;
            float4 ev;
            ev.x = (nib & 1u) ? __expf(s[0]) * rsinv : 0.f;
            ev.y = (nib & 2u) ? __expf(s[1]) * rsinv : 0.f;
            ev.z = (nib & 4u) ? __expf(s[2]) * rsinv : 0.f;
            ev.w = (nib & 8u) ? __expf(s[3]) * rsinv : 0.f;
            // attn: row i_row, cols c0 + nt*16 + 4g .. +3  (f32, exact)
            *(float4*)(arow + c0 + nt * 16 + g * 4) = ev;
            // P (bf16) for PV: row = q-local, col = k-local
            unsigned long long pk =
                  (unsigned long long)f2bf(ev.x)
                | ((unsigned long long)f2bf(ev.y) << 16)
                | ((unsigned long long)f2bf(ev.z) << 32)
                | ((unsigned long long)f2bf(ev.w) << 48);
            *(unsigned long long*)(prow + ((nt * 32 + g * 8) ^ swp)) = pk;
        }

        // PV: A = P (q x k), B = V (k x d)
        const char* pbase = (const char*)&P_lds[wave][0] + (lane & 15) * 128;
        bf16x8 pa0 = *(const bf16x8*)(pbase + ((g * 16) ^ swp));
        bf16x8 pa1 = *(const bf16x8*)(pbase + ((g * 16 + 64) ^ swp));
        #pragma unroll
        for (int dt = 0; dt < 4; ++dt) {
            int vrow = dt * 16 + (lane & 15);
            const char* vbase = (const char*)V_lds + vrow * 128;
            int sw = (vrow & 7) << 4;
            bf16x8 vb0 = *(const bf16x8*)(vbase + ((g * 16) ^ sw));
            bf16x8 vb1 = *(const bf16x8*)(vbase + ((g * 16 + 64) ^ sw));
            o[dt] = MFMA16(pa0, vb0, o[dt]);
            o[dt] = MFMA16(pa1, vb1, o[dt]);
        }
    }

    // ---------------- ctx store (bf16): row = 4g+r q-local, col = dt*16+(lane&15)
    #pragma unroll
    for (int dt = 0; dt < 4; ++dt) {
        int d = dt * 16 + (lane & 15);
        #pragma unroll
        for (int r = 0; r < 4; ++r) {
            int i = i0 + wave * 16 + g * 4 + r;
            ctxb[((size_t)(b * SEQ + i)) * DMODEL + h * DEPTH + d] = f2bf(o[dt][r]);
        }
    }
}

// ---------------------------------------------------------------------------
extern "C" void kernel_launch(void* const* d_in, const int* in_sizes, int n_in,
                              void* d_out, int out_size, void* d_ws, size_t ws_size,
                              hipStream_t stream) {
    const float* v  = (const float*)d_in[0];
    const float* k  = (const float*)d_in[1];
    const float* q  = (const float*)d_in[2];
    const float* Wq = (const float*)d_in[3];
    const float* bq = (const float*)d_in[4];
    const float* Wk = (const float*)d_in[5];
    const float* bk = (const float*)d_in[6];
    const float* Wv = (const float*)d_in[7];
    const float* bv = (const float*)d_in[8];
    const float* Wo = (const float*)d_in[9];
    const float* bo = (const float*)d_in[10];

    float* out  = (float*)d_out;                   // [B*S, D]
    float* attn = out + 4194304;                   // [B, H, S, S]  (512 MB)

    // --- d_ws layout (60 MB) ---
    float* ws = (float*)d_ws;
    float* vh = ws;                                          // 16 MB f32
    unsigned short* qbb  = (unsigned short*)(ws + 4194304);  // 8 MB bf16
    unsigned short* kbb  = qbb  + 4194304;                   // 8 MB
    unsigned short* vbT  = kbb  + 4194304;                   // 8 MB
    unsigned short* ctxb = vbT  + 4194304;                   // 8 MB
    unsigned short* vb16 = ctxb + 4194304;                   // 8 MB
    unsigned short* WvT  = vb16 + 4194304;                   // 2 MB
    unsigned short* WoT  = WvT  + 1048576;                   // 2 MB

    // --- scratch inside attn region (overwritten by attn_mfma later) ---
    unsigned short* qs    = (unsigned short*)attn;           // [4096][3072] 24 MB
    unsigned short* ks    = qs + 12582912;                   // 24 MB
    unsigned short* WqTs  = ks + 12582912;                   // [1024][3072] 6 MB
    unsigned short* WkTs  = WqTs + 3145728;                  // 6 MB

    // converts
    cvt_split<<<2048, 256, 0, stream>>>(q, qs);
    cvt_split<<<2048, 256, 0, stream>>>(k, ks);
    cvt_plain<<<2048, 256, 0, stream>>>(v, vb16);
    cvt_wT<1><<<dim3(16, 16), 256, 0, stream>>>(Wq, WqTs);
    cvt_wT<1><<<dim3(16, 16), 256, 0, stream>>>(Wk, WkTs);
    cvt_wT<0><<<dim3(16, 16), 256, 0, stream>>>(Wv, WvT);
    cvt_wT<0><<<dim3(16, 16), 256, 0, stream>>>(Wo, WoT);

    // projections (MFMA): Q,K compensated split-bf16 (K=3072), V plain (K=1024)
    dim3 ggrid(8, 32);   // (N/128, M/128)
    gemm_mfma<1><<<ggrid, 256, 0, stream>>>(qs, WqTs, bq, qbb, 3072, 0.125f);
    gemm_mfma<1><<<ggrid, 256, 0, stream>>>(ks, WkTs, bk, kbb, 3072, 1.0f);
    gemm_mfma<0><<<ggrid, 256, 0, stream>>>(vb16, WvT, bv, vh, 1024, 1.0f);

    convert_vT<<<dim3(SEQ / 64, NHEAD, BATCH), 256, 0, stream>>>(vh, vbT);

    attn_mfma<<<dim3(SEQ / 64, NHEAD, BATCH), 256, 0, stream>>>(qbb, kbb, vbT, attn, ctxb);

    // output projection (bf16 MFMA, f32 out)
    gemm_mfma<0><<<ggrid, 256, 0, stream>>>(ctxb, WoT, bo, out, 1024, 1.0f);
}